// Round 8
// baseline (185.451 us; speedup 1.0000x reference)
//
#include <hip/hip_runtime.h>
#include <hip/hip_bf16.h>

// Problem constants (B,H,W,C = 32,32,32,256 -> l = 1024)
#define BATCH 32
#define L 1024
#define CD 256
#define NRT 8          // row panels of 128 (A side, preds)
#define NBT 8          // col tiles of 128 (B side, queries)
#define TILE_B 32768   // bf16 elements per B tile (128 x 256 = 64 KB)

typedef __bf16 bf16x8 __attribute__((ext_vector_type(8)));
typedef float  f32x4  __attribute__((ext_vector_type(4)));
typedef unsigned long long u64;

__device__ __forceinline__ unsigned int enc_f32(float f) {
    unsigned int u = __float_as_uint(f);
    return ((int)u < 0) ? ~u : (u | 0x80000000u);
}
__device__ __forceinline__ float dec_f32(unsigned int u) {
    u = (u & 0x80000000u) ? (u & 0x7FFFFFFFu) : ~u;
    return __uint_as_float(u);
}
__device__ __forceinline__ u64 pmax(u64 a, u64 b) { return a > b ? a : b; }

// async global->LDS, 16B/lane; LDS dest = wave-uniform base + lane*16.
__device__ __forceinline__ void gl_lds16(const __bf16* g, __bf16* l) {
    __builtin_amdgcn_global_load_lds(
        (const __attribute__((address_space(1))) unsigned int*)g,
        (__attribute__((address_space(3))) unsigned int*)l, 16, 0, 0);
}

// Kernel 0: fp32 -> bf16 convert into two consumer-exact layouts:
//  qsw  [b][ct(8)][step(4)][crow(128)][slot(8)x8]: LDS image for B tiles;
//       physical 16B slot s of a row holds logical k-slot (s ^ (crow&7))
//       (rule #21: swizzle source + read, gl_lds dest stays linear).
//  areg [b][rt(8)][wm(2)][f(32)][lane(64)]x8: per-LANE register image of A
//       fragments (f = tm*8 + step*2 + kk) -> mm loads A with fully
//       coalesced 16B/lane reads, no swizzle (registers have no banks).
__global__ __launch_bounds__(256) void convert_kernel(
    const float* __restrict__ qg,   // feats1 [B][L][CD] (queries)
    const float* __restrict__ pg,   // feats2 [B][L][CD] (preds)
    __bf16* __restrict__ qsw,
    __bf16* __restrict__ areg)
{
    const unsigned int t = blockIdx.x * 256 + threadIdx.x;   // 0..2M-1
    const unsigned int v = t & 0xFFFFFu;
    const float* src;
    __bf16* dst;
    if (t >> 20) {
        const int s    = v & 7;
        const int crow = (v >> 3) & 127;
        const int step = (v >> 10) & 3;
        const int ct   = (v >> 12) & 7;
        const int b    = v >> 15;
        src = qg + ((size_t)(b << 10) + (ct << 7) + crow) * CD
                 + (step << 6) + ((s ^ (crow & 7)) << 3);
        dst = qsw + (size_t)v * 8;
    } else {
        const int ln   = v & 63;
        const int f    = (v >> 6) & 31;
        const int wmv  = (v >> 11) & 1;
        const int rtv  = (v >> 12) & 7;
        const int b    = v >> 15;
        const int tm   = f >> 3;
        const int step = (f >> 1) & 3;
        const int kk   = f & 1;
        const int row  = (rtv << 7) + (wmv << 6) + (tm << 4) + (ln & 15);
        const int k    = (step << 6) + (((kk << 2) + (ln >> 4)) << 3);
        src = pg + ((size_t)(b << 10) + row) * CD + k;
        dst = areg + (size_t)v * 8;
    }
    const float4 f0 = *(const float4*)src;
    const float4 f1 = *(const float4*)(src + 4);
    bf16x8 o;
    o[0] = (__bf16)f0.x; o[1] = (__bf16)f0.y; o[2] = (__bf16)f0.z; o[3] = (__bf16)f0.w;
    o[4] = (__bf16)f1.x; o[5] = (__bf16)f1.y; o[6] = (__bf16)f1.z; o[7] = (__bf16)f1.w;
    *(bf16x8*)dst = o;
}

// Kernel 1: 256 blocks = 1/CU, single round. Block (b, rt) = 128 pred rows x
// all 1024 query cols. A lives ENTIRELY in registers (32 bf16x8/wave = 128
// VGPR, loaded once); B tiles (128 cols, 64 KB) stream through a 2-slot LDS
// ring via gload_lds with exact counted vmcnt (no vmem stores in the loop).
// 8 waves = 2(wm: 64 rows) x 4(wn: 32 cols); per (step,kk): 2 ds_reads feed
// 8 MFMAs.
// REGISTER BUDGET (r5/r7 lesson): the backend's DEFAULT occupancy heuristic
// targets 4 waves/EU -> 128 VGPR and spills afr to scratch (WRITE_SIZE 81 MB,
// mm 90 us) even though LDS (148 KB) already forces 1 block/CU = 2 waves/EU.
// amdgpu_waves_per_eu(2,2) pins the truth -> 256 VGPR budget, live ~220.
__global__ void __launch_bounds__(512)
__attribute__((amdgpu_waves_per_eu(2, 2)))
mm_argmax_kernel(
    const __bf16* __restrict__ qsw,
    const __bf16* __restrict__ areg,
    u64* __restrict__ colpart,   // [B][NRT][L] (enc(val)<<32)|~a
    int* __restrict__ max2)      // [B][L]
{
    __shared__ __bf16 sB[2][TILE_B];   // 128 KB
    __shared__ u64 sColW[2][L];        // 16 KB (col partials per wm)
    __shared__ u64 sRowW[4][128];      // 4 KB  (row partials per wn)

    const int tid = threadIdx.x;
    const int bid = blockIdx.x;
    // bid = rt*32 + b -> XCD = b%8 sticky: batch working set stays L2-local.
    const int b  = bid & 31;
    const int rt = bid >> 5;

    const int lane = tid & 63;
    const int w    = tid >> 6;
    const int wm   = w >> 2;      // 0..1: rows wm*64
    const int wn   = w & 3;       // 0..3: cols wn*32
    const int quad = lane >> 4;
    const int l16  = lane & 15;

    const __bf16* qb = qsw + (size_t)b * NBT * TILE_B;
    const __bf16* ab = areg + (size_t)((b * NRT + rt) * 2 + wm) * 32 * 512;

    // ---- A fragments -> registers (32 x bf16x8 = 128 VGPR), coalesced ----
    bf16x8 afr[32];
    #pragma unroll
    for (int f = 0; f < 32; ++f)
        afr[f] = *(const bf16x8*)&ab[f * 512 + lane * 8];
    __builtin_amdgcn_sched_barrier(0);   // pin issue order: A then B0 then B1

    // ---- B tiles 0,1 -> LDS ring (8 gl_lds per wave per tile) ----
    #pragma unroll
    for (int c = 0; c < 8; ++c)
        gl_lds16(qb + c * 4096 + tid * 8, &sB[0][c * 4096 + tid * 8]);
    __builtin_amdgcn_sched_barrier(0);
    #pragma unroll
    for (int c = 0; c < 8; ++c)
        gl_lds16(qb + TILE_B + c * 4096 + tid * 8, &sB[1][c * 4096 + tid * 8]);
    __builtin_amdgcn_sched_barrier(0);

    f32x4 acc[4][2];
    float rowv[4][4];
    int   rowj[4][4];
    #pragma unroll
    for (int tm = 0; tm < 4; ++tm)
        #pragma unroll
        for (int r = 0; r < 4; ++r) { rowv[tm][r] = -1e30f; rowj[tm][r] = 0; }

    const int a0q = rt * 128 + wm * 64 + quad * 4;   // + tm*16 + r

    #define COMPUTE(T)                                                         \
    {                                                                          \
        const __bf16* sBb = sB[(T) & 1];                                       \
        _Pragma("unroll")                                                      \
        for (int tm = 0; tm < 4; ++tm)                                         \
            _Pragma("unroll")                                                  \
            for (int tn = 0; tn < 2; ++tn) acc[tm][tn] = (f32x4){0.f,0.f,0.f,0.f}; \
        __builtin_amdgcn_s_setprio(1);                                         \
        _Pragma("unroll")                                                      \
        for (int step = 0; step < 4; ++step) {                                 \
            _Pragma("unroll")                                                  \
            for (int kk = 0; kk < 2; ++kk) {                                   \
                const int sw = ((kk * 4 + quad) ^ (l16 & 7)) << 3;             \
                bf16x8 b0 = *(const bf16x8*)&sBb[step * 8192 + (wn * 32      + l16) * 64 + sw]; \
                bf16x8 b1 = *(const bf16x8*)&sBb[step * 8192 + (wn * 32 + 16 + l16) * 64 + sw]; \
                _Pragma("unroll")                                              \
                for (int tm = 0; tm < 4; ++tm) {                               \
                    acc[tm][0] = __builtin_amdgcn_mfma_f32_16x16x32_bf16(      \
                        afr[tm * 8 + step * 2 + kk], b0, acc[tm][0], 0, 0, 0); \
                    acc[tm][1] = __builtin_amdgcn_mfma_f32_16x16x32_bf16(      \
                        afr[tm * 8 + step * 2 + kk], b1, acc[tm][1], 0, 0, 0); \
                }                                                              \
            }                                                                  \
        }                                                                      \
        __builtin_amdgcn_s_setprio(0);                                         \
        /* row running argmax (j ascends with T,tn; strict > = first index) */ \
        const int jb = (T) * 128 + wn * 32 + l16;                              \
        _Pragma("unroll")                                                      \
        for (int tm = 0; tm < 4; ++tm)                                         \
            _Pragma("unroll")                                                  \
            for (int r = 0; r < 4; ++r) {                                      \
                const float v0 = acc[tm][0][r], v1 = acc[tm][1][r];            \
                if (v0 > rowv[tm][r]) { rowv[tm][r] = v0; rowj[tm][r] = jb; }  \
                if (v1 > rowv[tm][r]) { rowv[tm][r] = v1; rowj[tm][r] = jb + 16; } \
            }                                                                  \
        /* col argmax over wave's 64 rows (ascending a), to LDS not global */  \
        _Pragma("unroll")                                                      \
        for (int tn = 0; tn < 2; ++tn) {                                       \
            float cv = acc[0][tn][0];                                          \
            int   ca = a0q;                                                    \
            _Pragma("unroll")                                                  \
            for (int tm = 0; tm < 4; ++tm)                                     \
                _Pragma("unroll")                                              \
                for (int r = 0; r < 4; ++r) {                                  \
                    if (tm == 0 && r == 0) continue;                           \
                    if (acc[tm][tn][r] > cv) { cv = acc[tm][tn][r]; ca = a0q + tm * 16 + r; } \
                }                                                              \
            u64 pk = ((u64)enc_f32(cv) << 32) | (unsigned int)(~(unsigned int)ca); \
            pk = pmax(pk, __shfl_xor(pk, 16));                                 \
            pk = pmax(pk, __shfl_xor(pk, 32));                                 \
            if (quad == 0) sColW[wm][(T) * 128 + wn * 32 + tn * 16 + l16] = pk; \
        }                                                                      \
    }

    // per-iter: gate B(T) [own 8 gl_lds; newer = B(T+1)'s 8 -> vmcnt(8),
    // except last tile -> 0], barrier, compute, barrier, issue B(T+2).
    #define TILE_ITER(T, VM)                                                   \
        asm volatile("s_waitcnt vmcnt(" #VM ")" ::: "memory");                 \
        __builtin_amdgcn_s_barrier();                                          \
        __builtin_amdgcn_sched_barrier(0);                                     \
        COMPUTE(T)                                                             \
        __builtin_amdgcn_s_barrier();                                          \
        __builtin_amdgcn_sched_barrier(0);                                     \
        if ((T) + 2 < NBT) {                                                   \
            _Pragma("unroll")                                                  \
            for (int c = 0; c < 8; ++c)                                        \
                gl_lds16(qb + (size_t)((T) + 2) * TILE_B + c * 4096 + tid * 8, \
                         &sB[(T) & 1][c * 4096 + tid * 8]);                    \
            __builtin_amdgcn_sched_barrier(0);                                 \
        }

    TILE_ITER(0, 8)
    TILE_ITER(1, 8)
    TILE_ITER(2, 8)
    TILE_ITER(3, 8)
    TILE_ITER(4, 8)
    TILE_ITER(5, 8)
    TILE_ITER(6, 8)
    TILE_ITER(7, 0)

    #undef TILE_ITER
    #undef COMPUTE

    // ---- row argmax finish: reduce over l16 lanes, combine 4 wn via LDS ----
    #pragma unroll
    for (int tm = 0; tm < 4; ++tm)
        #pragma unroll
        for (int r = 0; r < 4; ++r) {
            u64 pk = ((u64)enc_f32(rowv[tm][r]) << 32)
                   | (unsigned int)(~(unsigned int)rowj[tm][r]);
            pk = pmax(pk, __shfl_xor(pk, 1));
            pk = pmax(pk, __shfl_xor(pk, 2));
            pk = pmax(pk, __shfl_xor(pk, 4));
            pk = pmax(pk, __shfl_xor(pk, 8));
            if (l16 == 0) sRowW[wn][wm * 64 + tm * 16 + quad * 4 + r] = pk;
        }
    __syncthreads();
    if (tid < 128) {
        const u64 m = pmax(pmax(sRowW[0][tid], sRowW[1][tid]),
                           pmax(sRowW[2][tid], sRowW[3][tid]));
        max2[(size_t)b * L + rt * 128 + tid] = (int)(~(unsigned int)m) & (L - 1);
    }
    #pragma unroll
    for (int c0 = 0; c0 < 2; ++c0) {
        const int c = c0 * 512 + tid;
        colpart[(size_t)(b * NRT + rt) * L + c] = pmax(sColW[0][c], sColW[1][c]);
    }
}

// Kernel 2: reduce col partials (8-deep) + mutual-NN + mean. 1 block/batch.
__global__ __launch_bounds__(1024) void finalize_kernel(
    const u64* __restrict__ colpart,  // [B][NRT][L]
    const int* __restrict__ max2,     // [B][L]
    float* __restrict__ out)
{
    __shared__ int sMax2[L];
    __shared__ float sSum[16];
    __shared__ int sCnt[16];
    const int b = blockIdx.x;
    const int j = threadIdx.x;        // 0..1023

    sMax2[j] = max2[(size_t)b * L + j];

    u64 cb = 0ull;
    #pragma unroll
    for (int k = 0; k < NRT; ++k)
        cb = pmax(cb, colpart[(size_t)(b * NRT + k) * L + j]);
    __syncthreads();

    const int a = (int)(~(unsigned int)cb) & (L - 1);      // max1[j]
    const float val = dec_f32((unsigned int)(cb >> 32));   // sims[j]
    const bool mut = (sMax2[a] == j);                      // mutual NN
    float sum = mut ? val : 0.f;
    int   cnt = mut ? 1 : 0;

    #pragma unroll
    for (int o = 32; o >= 1; o >>= 1) {
        sum += __shfl_down(sum, o);
        cnt += __shfl_down(cnt, o);
    }
    if ((j & 63) == 0) { sSum[j >> 6] = sum; sCnt[j >> 6] = cnt; }
    __syncthreads();
    if (j == 0) {
        float S = 0.f;
        int   C = 0;
        #pragma unroll
        for (int i = 0; i < 16; ++i) { S += sSum[i]; C += sCnt[i]; }
        out[b] = S / fmaxf((float)C, 1.0f);
    }
}

extern "C" void kernel_launch(void* const* d_in, const int* in_sizes, int n_in,
                              void* d_out, int out_size, void* d_ws, size_t ws_size,
                              hipStream_t stream) {
    const float* q = (const float*)d_in[0];   // feats1 (queries)
    const float* p = (const float*)d_in[1];   // feats2 (preds)
    float* out = (float*)d_out;

    // ws layout: colpart [32][8][1024] u64 (2 MiB) | max2 [32][1024] int
    // (128 KiB) | areg bf16 (16 MiB) | qsw bf16 (16 MiB). ~34 MiB total.
    // Every slot written before read -> no init needed.
    u64* colpart = (u64*)d_ws;
    int* max2 = (int*)(colpart + (size_t)BATCH * NRT * L);
    __bf16* areg = (__bf16*)((char*)d_ws + (2u << 20) + (128u << 10));
    __bf16* qsw = areg + (size_t)8388608;

    convert_kernel<<<8192, 256, 0, stream>>>(q, p, qsw, areg);
    mm_argmax_kernel<<<BATCH * NRT, 512, 0, stream>>>(qsw, areg, colpart, max2);
    finalize_kernel<<<BATCH, 1024, 0, stream>>>(colpart, max2, out);
}

// Round 9
// 150.696 us; speedup vs baseline: 1.2306x; 1.2306x over previous
//
#include <hip/hip_runtime.h>
#include <hip/hip_bf16.h>

// Problem constants (B,H,W,C = 32,32,32,256 -> l = 1024)
#define BATCH 32
#define L 1024
#define CD 256
#define NRT 8          // row panels of 128 (A side, preds)
#define NPOS 8         // col positions of 128 (B side, queries)
#define NHT 16         // streamed half-tiles: pos*2 + khalf
#define HT_E 16384     // bf16 elems per half-tile (128 cols x 128 k = 32 KB)

typedef __bf16 bf16x8 __attribute__((ext_vector_type(8)));
typedef float  f32x4  __attribute__((ext_vector_type(4)));
typedef unsigned long long u64;

__device__ __forceinline__ unsigned int enc_f32(float f) {
    unsigned int u = __float_as_uint(f);
    return ((int)u < 0) ? ~u : (u | 0x80000000u);
}
__device__ __forceinline__ float dec_f32(unsigned int u) {
    u = (u & 0x80000000u) ? (u & 0x7FFFFFFFu) : ~u;
    return __uint_as_float(u);
}
__device__ __forceinline__ u64 pmax(u64 a, u64 b) { return a > b ? a : b; }

// async global->LDS, 16B/lane; LDS dest = wave-uniform base + lane*16.
__device__ __forceinline__ void gl_lds16(const __bf16* g, __bf16* l) {
    __builtin_amdgcn_global_load_lds(
        (const __attribute__((address_space(1))) unsigned int*)g,
        (__attribute__((address_space(3))) unsigned int*)l, 16, 0, 0);
}

// Kernel 0 (R4-proven, verbatim): fp32 -> bf16 convert into PRE-SWIZZLED
// tiled layouts = exact LDS images (rule #21: swizzle source + read, linear
// gl_lds dest):
//   psw: [b][rt(8)][step(4)][row(128)][64k]   A panels (64 KB each)
//   qsw: [b][ct(8)][step(4)][crow(128)][64k]  B tiles; step(4)=kh(2)*2+s(2)
// 16B slot s of a row holds input k-slot (s ^ (row&7)) of that step's range.
__global__ __launch_bounds__(256) void convert_kernel(
    const float* __restrict__ qg,   // feats1 [B][L][CD] (queries)
    const float* __restrict__ pg,   // feats2 [B][L][CD] (preds)
    __bf16* __restrict__ qsw,
    __bf16* __restrict__ psw)
{
    const unsigned int t = blockIdx.x * 256 + threadIdx.x;   // 0..2M-1
    const unsigned int v = t & 0xFFFFFu;
    const float* src;
    __bf16* dst;
    if (t >> 20) {
        const int s    = v & 7;
        const int crow = (v >> 3) & 127;
        const int step = (v >> 10) & 3;
        const int ct   = (v >> 12) & 7;
        const int b    = v >> 15;
        src = qg + ((size_t)(b << 10) + (ct << 7) + crow) * CD
                 + (step << 6) + ((s ^ (crow & 7)) << 3);
        dst = qsw + (size_t)v * 8;
    } else {
        const int s    = v & 7;
        const int row  = (v >> 3) & 127;
        const int step = (v >> 10) & 3;
        const int pan  = (v >> 12) & 7;
        const int b    = v >> 15;
        src = pg + ((size_t)(b << 10) + (pan << 7) + row) * CD
                 + (step << 6) + ((s ^ (row & 7)) << 3);
        dst = psw + (size_t)v * 8;
    }
    const float4 f0 = *(const float4*)src;
    const float4 f1 = *(const float4*)(src + 4);
    bf16x8 o;
    o[0] = (__bf16)f0.x; o[1] = (__bf16)f0.y; o[2] = (__bf16)f0.z; o[3] = (__bf16)f0.w;
    o[4] = (__bf16)f1.x; o[5] = (__bf16)f1.y; o[6] = (__bf16)f1.z; o[7] = (__bf16)f1.w;
    *(bf16x8*)dst = o;
}

// Kernel 1: 256 blocks = 1/CU, single round. Block (b, rt) = 128 pred rows x
// all 1024 query cols. A panel (64 KB, full K) LDS-resident; B streams as 16
// half-tiles (128 cols x 128 k = 32 KB) through a RING-3 (96 KB) via gl_lds.
// LDS = 64 + 96 = exactly 160 KiB; row-partial buffer aliased into a dead
// ring slot. ONE barrier per half-tile: the gate-barrier of ht(i) proves all
// waves finished compute(i-1), so ht(i+2) -> buf((i+2)%3) (= compute(i-1)'s
// buffer) is safe to issue right after it. Steady gate = vmcnt(4).
// 8 waves = 4(wm: 32 rows) x 2(wn: 64 cols); wave tile 32x64, acc 2x4:
// 6 ds_read_b128 feed 8 MFMAs. Live VGPR ~90 — fits the backend's hard
// 128/wave cap at 512 thr (r5/7/8: A-in-reg at ~220 live always spills).
__global__ __launch_bounds__(512) void mm_argmax_kernel(
    const __bf16* __restrict__ qsw,
    const __bf16* __restrict__ psw,
    u64* __restrict__ colpart,   // [B][NRT*4][L] (enc(val)<<32)|~a
    int* __restrict__ max2)      // [B][L]
{
    __shared__ __bf16 sA[4 * 8192];    // 64 KB: [step4][row128][64]
    __shared__ __bf16 sB[3 * HT_E];    // 96 KB ring
    // aliased row-partial buffer (2 KB) inside ring slot 1: slot 1 last holds
    // ht13 (13%3==1), whose readers finish before the final reduce writes.
    u64* sRowW = (u64*)&sB[HT_E];      // [wn(2)][row(128)]

    const int tid = threadIdx.x;
    const int bid = blockIdx.x;
    // bid = rt*32 + b -> XCD = b%8 sticky: batch working set stays L2-local.
    const int b  = bid & 31;
    const int rt = bid >> 5;

    const int lane = tid & 63;
    const int w    = tid >> 6;
    const int wm   = w >> 1;      // 0..3: rows wm*32
    const int wn   = w & 1;       // 0..1: cols wn*64
    const int quad = lane >> 4;
    const int l16  = lane & 15;

    const __bf16* pa = psw + (size_t)(b * NRT + rt) * (4 * 8192);
    const __bf16* qb = qsw + (size_t)b * (NPOS * 2 * HT_E);

    // ---- prologue: A panel (8 chunks) + half-tiles 0,1 (4 chunks each) ----
    #pragma unroll
    for (int c = 0; c < 8; ++c)
        gl_lds16(pa + c * 4096 + tid * 8, &sA[c * 4096 + tid * 8]);
    #pragma unroll
    for (int h = 0; h < 2; ++h)
        #pragma unroll
        for (int c = 0; c < 4; ++c)
            gl_lds16(qb + h * HT_E + c * 4096 + tid * 8,
                     &sB[h * HT_E + c * 4096 + tid * 8]);
    __builtin_amdgcn_sched_barrier(0);

    f32x4 acc[2][4];
    float rowv[2][4];
    int   rowj[2][4];
    #pragma unroll
    for (int tm = 0; tm < 2; ++tm)
        #pragma unroll
        for (int r = 0; r < 4; ++r) { rowv[tm][r] = -1e30f; rowj[tm][r] = 0; }

    const int a0q = rt * 128 + wm * 32 + quad * 4;         // + tm*16 + r
    const size_t colbase = ((size_t)(b * NRT + rt) * 4 + wm) * L;

    #define COMPUTE(HT)                                                        \
    {                                                                          \
        const __bf16* sBb = &sB[((HT) % 3) * HT_E];                            \
        if (((HT) & 1) == 0) {                                                 \
            _Pragma("unroll")                                                  \
            for (int tm = 0; tm < 2; ++tm)                                     \
                _Pragma("unroll")                                              \
                for (int tn = 0; tn < 4; ++tn)                                 \
                    acc[tm][tn] = (f32x4){0.f, 0.f, 0.f, 0.f};                 \
        }                                                                      \
        __builtin_amdgcn_s_setprio(1);                                         \
        _Pragma("unroll")                                                      \
        for (int step = 0; step < 2; ++step) {                                 \
            _Pragma("unroll")                                                  \
            for (int kk = 0; kk < 2; ++kk) {                                   \
                const int sw = ((kk * 4 + quad) ^ (l16 & 7)) << 3;             \
                const int ks = ((HT) & 1) * 2 + step;                          \
                bf16x8 a0 = *(const bf16x8*)&sA[ks * 8192 + (wm * 32      + l16) * 64 + sw]; \
                bf16x8 a1 = *(const bf16x8*)&sA[ks * 8192 + (wm * 32 + 16 + l16) * 64 + sw]; \
                bf16x8 b0 = *(const bf16x8*)&sBb[step * 8192 + (wn * 64      + l16) * 64 + sw]; \
                bf16x8 b1 = *(const bf16x8*)&sBb[step * 8192 + (wn * 64 + 16 + l16) * 64 + sw]; \
                bf16x8 b2 = *(const bf16x8*)&sBb[step * 8192 + (wn * 64 + 32 + l16) * 64 + sw]; \
                bf16x8 b3 = *(const bf16x8*)&sBb[step * 8192 + (wn * 64 + 48 + l16) * 64 + sw]; \
                acc[0][0] = __builtin_amdgcn_mfma_f32_16x16x32_bf16(a0, b0, acc[0][0], 0, 0, 0); \
                acc[0][1] = __builtin_amdgcn_mfma_f32_16x16x32_bf16(a0, b1, acc[0][1], 0, 0, 0); \
                acc[0][2] = __builtin_amdgcn_mfma_f32_16x16x32_bf16(a0, b2, acc[0][2], 0, 0, 0); \
                acc[0][3] = __builtin_amdgcn_mfma_f32_16x16x32_bf16(a0, b3, acc[0][3], 0, 0, 0); \
                acc[1][0] = __builtin_amdgcn_mfma_f32_16x16x32_bf16(a1, b0, acc[1][0], 0, 0, 0); \
                acc[1][1] = __builtin_amdgcn_mfma_f32_16x16x32_bf16(a1, b1, acc[1][1], 0, 0, 0); \
                acc[1][2] = __builtin_amdgcn_mfma_f32_16x16x32_bf16(a1, b2, acc[1][2], 0, 0, 0); \
                acc[1][3] = __builtin_amdgcn_mfma_f32_16x16x32_bf16(a1, b3, acc[1][3], 0, 0, 0); \
            }                                                                  \
        }                                                                      \
        __builtin_amdgcn_s_setprio(0);                                         \
    }

    // epilogue for position P (after its second half-tile accumulated)
    #define EPILOGUE(P)                                                        \
    {                                                                          \
        const int jb = (P) * 128 + wn * 64 + l16;                              \
        _Pragma("unroll")                                                      \
        for (int tm = 0; tm < 2; ++tm)                                         \
            _Pragma("unroll")                                                  \
            for (int r = 0; r < 4; ++r)                                        \
                _Pragma("unroll")                                              \
                for (int tn = 0; tn < 4; ++tn) {                               \
                    const float v_ = acc[tm][tn][r];                           \
                    if (v_ > rowv[tm][r]) { rowv[tm][r] = v_; rowj[tm][r] = jb + tn * 16; } \
                }                                                              \
        _Pragma("unroll")                                                      \
        for (int tn = 0; tn < 4; ++tn) {                                       \
            float cv = acc[0][tn][0];                                          \
            int   ca = a0q;                                                    \
            _Pragma("unroll")                                                  \
            for (int tm = 0; tm < 2; ++tm)                                     \
                _Pragma("unroll")                                              \
                for (int r = 0; r < 4; ++r) {                                  \
                    if (tm == 0 && r == 0) continue;                           \
                    if (acc[tm][tn][r] > cv) { cv = acc[tm][tn][r]; ca = a0q + tm * 16 + r; } \
                }                                                              \
            u64 pk = ((u64)enc_f32(cv) << 32) | (unsigned int)(~(unsigned int)ca); \
            pk = pmax(pk, __shfl_xor(pk, 16));                                 \
            pk = pmax(pk, __shfl_xor(pk, 32));                                 \
            if (quad == 0)                                                     \
                colpart[colbase + (P) * 128 + wn * 64 + tn * 16 + l16] = pk;   \
        }                                                                      \
    }

    // one barrier per half-tile; gate vmcnt(4) = ht(i+1)'s 4 loads outstanding
    #define HT_ITER(HT, VM)                                                    \
        asm volatile("s_waitcnt vmcnt(" #VM ")" ::: "memory");                 \
        __builtin_amdgcn_s_barrier();                                          \
        __builtin_amdgcn_sched_barrier(0);                                     \
        if ((HT) + 2 < NHT) {                                                  \
            _Pragma("unroll")                                                  \
            for (int c = 0; c < 4; ++c)                                        \
                gl_lds16(qb + (size_t)((HT) + 2) * HT_E + c * 4096 + tid * 8,  \
                         &sB[(((HT) + 2) % 3) * HT_E + c * 4096 + tid * 8]);   \
            __builtin_amdgcn_sched_barrier(0);                                 \
        }                                                                      \
        COMPUTE(HT)                                                            \
        if ((HT) & 1) EPILOGUE((HT) >> 1)

    HT_ITER(0, 4)  HT_ITER(1, 4)  HT_ITER(2, 4)  HT_ITER(3, 4)
    HT_ITER(4, 4)  HT_ITER(5, 4)  HT_ITER(6, 4)  HT_ITER(7, 4)
    HT_ITER(8, 4)  HT_ITER(9, 4)  HT_ITER(10, 4) HT_ITER(11, 4)
    HT_ITER(12, 4) HT_ITER(13, 4) HT_ITER(14, 4) HT_ITER(15, 0)

    #undef HT_ITER
    #undef EPILOGUE
    #undef COMPUTE

    // ---- row argmax finish: reduce over l16 lanes, combine wn via LDS ----
    // (sRowW aliases ring slot 1; last compute read slot 0, so no live reader)
    #pragma unroll
    for (int tm = 0; tm < 2; ++tm)
        #pragma unroll
        for (int r = 0; r < 4; ++r) {
            u64 pk = ((u64)enc_f32(rowv[tm][r]) << 32)
                   | (unsigned int)(~(unsigned int)rowj[tm][r]);
            pk = pmax(pk, __shfl_xor(pk, 1));
            pk = pmax(pk, __shfl_xor(pk, 2));
            pk = pmax(pk, __shfl_xor(pk, 4));
            pk = pmax(pk, __shfl_xor(pk, 8));
            if (l16 == 0)
                sRowW[wn * 128 + wm * 32 + tm * 16 + quad * 4 + r] = pk;
        }
    __syncthreads();
    if (tid < 128) {
        const u64 m = pmax(sRowW[tid], sRowW[128 + tid]);
        max2[(size_t)b * L + rt * 128 + tid] = (int)(~(unsigned int)m) & (L - 1);
    }
}

// Kernel 2: reduce col partials (32-deep: rt x wm) + mutual-NN + mean.
__global__ __launch_bounds__(1024) void finalize_kernel(
    const u64* __restrict__ colpart,  // [B][32][L]
    const int* __restrict__ max2,     // [B][L]
    float* __restrict__ out)
{
    __shared__ int sMax2[L];
    __shared__ float sSum[16];
    __shared__ int sCnt[16];
    const int b = blockIdx.x;
    const int j = threadIdx.x;        // 0..1023

    sMax2[j] = max2[(size_t)b * L + j];

    u64 cb = 0ull;
    #pragma unroll
    for (int k = 0; k < 32; ++k)
        cb = pmax(cb, colpart[((size_t)b * 32 + k) * L + j]);
    __syncthreads();

    const int a = (int)(~(unsigned int)cb) & (L - 1);      // max1[j]
    const float val = dec_f32((unsigned int)(cb >> 32));   // sims[j]
    const bool mut = (sMax2[a] == j);                      // mutual NN
    float sum = mut ? val : 0.f;
    int   cnt = mut ? 1 : 0;

    #pragma unroll
    for (int o = 32; o >= 1; o >>= 1) {
        sum += __shfl_down(sum, o);
        cnt += __shfl_down(cnt, o);
    }
    if ((j & 63) == 0) { sSum[j >> 6] = sum; sCnt[j >> 6] = cnt; }
    __syncthreads();
    if (j == 0) {
        float S = 0.f;
        int   C = 0;
        #pragma unroll
        for (int i = 0; i < 16; ++i) { S += sSum[i]; C += sCnt[i]; }
        out[b] = S / fmaxf((float)C, 1.0f);
    }
}

extern "C" void kernel_launch(void* const* d_in, const int* in_sizes, int n_in,
                              void* d_out, int out_size, void* d_ws, size_t ws_size,
                              hipStream_t stream) {
    const float* q = (const float*)d_in[0];   // feats1 (queries)
    const float* p = (const float*)d_in[1];   // feats2 (preds)
    float* out = (float*)d_out;

    // ws layout: colpart [32][32][1024] u64 (8 MiB) | max2 [32][1024] int
    // (128 KiB, padded to 512 KiB) | psw bf16 (16 MiB) | qsw bf16 (16 MiB).
    // Every slot written before read -> no init needed.
    u64* colpart = (u64*)d_ws;
    int* max2 = (int*)(colpart + (size_t)BATCH * 32 * L);
    __bf16* psw = (__bf16*)((char*)d_ws + (8u << 20) + (512u << 10));
    __bf16* qsw = psw + (size_t)8388608;

    convert_kernel<<<8192, 256, 0, stream>>>(q, p, qsw, psw);
    mm_argmax_kernel<<<BATCH * NRT, 512, 0, stream>>>(qsw, psw, colpart, max2);
    finalize_kernel<<<BATCH, 1024, 0, stream>>>(colpart, max2, out);
}

// Round 10
// 142.799 us; speedup vs baseline: 1.2987x; 1.0553x over previous
//
#include <hip/hip_runtime.h>
#include <hip/hip_bf16.h>

// Problem constants (B,H,W,C = 32,32,32,256 -> l = 1024)
#define BATCH 32
#define L 1024
#define CD 256
#define NRT 16         // row panels of 64 (A side, preds)
#define NQT 32         // streamed B quarter-tiles: pos(8) x ks(4)

typedef __bf16 bf16x8 __attribute__((ext_vector_type(8)));
typedef float  f32x4  __attribute__((ext_vector_type(4)));
typedef unsigned long long u64;

__device__ __forceinline__ unsigned int enc_f32(float f) {
    unsigned int u = __float_as_uint(f);
    return ((int)u < 0) ? ~u : (u | 0x80000000u);
}
__device__ __forceinline__ float dec_f32(unsigned int u) {
    u = (u & 0x80000000u) ? (u & 0x7FFFFFFFu) : ~u;
    return __uint_as_float(u);
}
__device__ __forceinline__ u64 pmax(u64 a, u64 b) { return a > b ? a : b; }
__device__ __forceinline__ bf16x8 cvt8(float4 a, float4 b) {
    bf16x8 o;
    o[0] = (__bf16)a.x; o[1] = (__bf16)a.y; o[2] = (__bf16)a.z; o[3] = (__bf16)a.w;
    o[4] = (__bf16)b.x; o[5] = (__bf16)b.y; o[6] = (__bf16)b.z; o[7] = (__bf16)b.w;
    return o;
}

// SINGLE fused kernel (convert pass deleted — r9 lesson: convert(25us)+gl_lds
// never beat inline cvt; reg-staging also lets us ds_write swizzled directly).
// 512 blocks = 2/CU (the r4/r9 fix: two INDEPENDENT barrier groups per CU so
// one block's gate stalls overlap the other's compute; 1-block/CU lockstep
// measured 4x above pipe floors). Block (b, rt) = 64 pred rows x 1024 cols.
// 256 thr = 4 waves (2 wm x 2 wn), wave tile 32x64, acc 2x4.
// A (64x256 bf16, 32 KB) staged once fp32->bf16. B streams as 32 quarter-tiles
// (128 cols x 64 k = 16 KB) through a 2-slot ring, reg-staged (T14: issue
// loads pre-MFMA, cvt+ds_write post-MFMA; compiler's counted vmcnt gates).
// LDS 32+32+1 = 66.5 KB -> 2 blocks/CU. Live VGPR ~120 (fits the observed
// hard 128 cap: pf 32 + acc 32 + rowbest 16 + transients/addr ~40).
// Swizzle: physical 16B slot s of a row holds logical k-slot s^(row&7);
// ds_write addresses are linear per wave (conflict-free), reads XOR back.
__global__ void __launch_bounds__(256)
__attribute__((amdgpu_waves_per_eu(2)))
mm_argmax_kernel(
    const float* __restrict__ qg,   // feats1 [B][L][CD] (queries)
    const float* __restrict__ pg,   // feats2 [B][L][CD] (preds)
    u64* __restrict__ colpart,      // [B][32][L] (enc(val)<<32)|~a
    int* __restrict__ max2)         // [B][L]
{
    __shared__ __bf16 sA[4 * 4096];    // 32 KB: [ks4][row64][64]
    __shared__ __bf16 sB[2][8192];     // 2 x 16 KB: [crow128][64]
    __shared__ u64 sRow[2][64];        // 1 KB

    const int tid = threadIdx.x;
    const int bid = blockIdx.x;
    // bid = rt*32 + b -> XCD = b%8 sticky; co-resident pair (bid, bid+256) is
    // the SAME batch (256%8==0) -> shared B stream in L2.
    const int b  = bid & 31;
    const int rt = bid >> 5;

    const int lane = tid & 63;
    const int w    = tid >> 6;
    const int wm   = w >> 1;      // 0..1: rows wm*32
    const int wn   = w & 1;       // 0..1: cols wn*64
    const int quad = lane >> 4;
    const int l16  = lane & 15;

    const float* pA = pg + ((size_t)b * L + rt * 64) * CD;
    const float* pQ = qg + (size_t)b * L * CD;

    // ---- stage A panel (64x256) fp32 -> bf16, two passes of 4 slots ----
    // slot sid (16B out, 32B in): row=sid>>5, ks=(sid>>3)&3, sl=sid&7.
    #pragma unroll
    for (int pass = 0; pass < 2; ++pass) {
        float4 t[8];
        #pragma unroll
        for (int s = 0; s < 4; ++s) {
            const int sid = (pass * 4 + s) * 256 + tid;
            const int row = sid >> 5;
            const int ks  = (sid >> 3) & 3;
            const int sl  = sid & 7;
            const float* src = pA + row * CD + ks * 64 + ((sl ^ (row & 7)) << 3);
            t[2 * s]     = ((const float4*)src)[0];
            t[2 * s + 1] = ((const float4*)src)[1];
        }
        #pragma unroll
        for (int s = 0; s < 4; ++s) {
            const int sid = (pass * 4 + s) * 256 + tid;
            const int row = sid >> 5;
            const int ks  = (sid >> 3) & 3;
            const int sl  = sid & 7;
            *(bf16x8*)&sA[ks * 4096 + row * 64 + sl * 8] = cvt8(t[2 * s], t[2 * s + 1]);
        }
    }
    // ---- stage B quarter-tile 0 (pos 0, ks 0) ----
    {
        float4 t[8];
        #pragma unroll
        for (int s = 0; s < 4; ++s) {
            const int sid  = s * 256 + tid;
            const int crow = sid >> 3;
            const int sl   = sid & 7;
            const float* src = pQ + (size_t)crow * CD + ((sl ^ (crow & 7)) << 3);
            t[2 * s]     = ((const float4*)src)[0];
            t[2 * s + 1] = ((const float4*)src)[1];
        }
        #pragma unroll
        for (int s = 0; s < 4; ++s) {
            const int sid  = s * 256 + tid;
            const int crow = sid >> 3;
            const int sl   = sid & 7;
            *(bf16x8*)&sB[0][crow * 64 + sl * 8] = cvt8(t[2 * s], t[2 * s + 1]);
        }
    }

    f32x4 acc[2][4];
    u64 rowbest[2][4];
    #pragma unroll
    for (int tm = 0; tm < 2; ++tm)
        #pragma unroll
        for (int r = 0; r < 4; ++r) rowbest[tm][r] = 0ull;

    const int a0q = rt * 64 + wm * 32 + quad * 4;          // + tm*16 + r
    const size_t colbase = ((size_t)b * 32 + rt * 2 + wm) * L;

    float4 pf[8];

    #pragma unroll 4
    for (int t = 0; t < NQT; ++t) {
        // B1: qt(t)'s ds_writes visible to all waves
        asm volatile("s_waitcnt lgkmcnt(0)" ::: "memory");
        __builtin_amdgcn_s_barrier();
        __builtin_amdgcn_sched_barrier(0);

        // issue qt(t+1) global loads -> regs (latency hides under MFMAs)
        if (t < NQT - 1) {
            const int pos1 = (t + 1) >> 2, ks1 = (t + 1) & 3;
            #pragma unroll
            for (int s = 0; s < 4; ++s) {
                const int sid  = s * 256 + tid;
                const int crow = sid >> 3;
                const int sl   = sid & 7;
                const float* src = pQ + (size_t)(pos1 * 128 + crow) * CD
                                 + ks1 * 64 + ((sl ^ (crow & 7)) << 3);
                pf[2 * s]     = ((const float4*)src)[0];
                pf[2 * s + 1] = ((const float4*)src)[1];
            }
            __builtin_amdgcn_sched_barrier(0);
        }

        // compute qt(t): 16 MFMA
        const int ks = t & 3;
        const __bf16* sBb = sB[t & 1];
        if (ks == 0) {
            #pragma unroll
            for (int tm = 0; tm < 2; ++tm)
                #pragma unroll
                for (int tn = 0; tn < 4; ++tn) acc[tm][tn] = (f32x4){0.f, 0.f, 0.f, 0.f};
        }
        __builtin_amdgcn_s_setprio(1);
        #pragma unroll
        for (int kk = 0; kk < 2; ++kk) {
            const int sw = ((kk * 4 + quad) ^ (l16 & 7)) << 3;
            bf16x8 a0 = *(const bf16x8*)&sA[ks * 4096 + (wm * 32      + l16) * 64 + sw];
            bf16x8 a1 = *(const bf16x8*)&sA[ks * 4096 + (wm * 32 + 16 + l16) * 64 + sw];
            bf16x8 b0 = *(const bf16x8*)&sBb[(wn * 64      + l16) * 64 + sw];
            bf16x8 b1 = *(const bf16x8*)&sBb[(wn * 64 + 16 + l16) * 64 + sw];
            bf16x8 b2 = *(const bf16x8*)&sBb[(wn * 64 + 32 + l16) * 64 + sw];
            bf16x8 b3 = *(const bf16x8*)&sBb[(wn * 64 + 48 + l16) * 64 + sw];
            acc[0][0] = __builtin_amdgcn_mfma_f32_16x16x32_bf16(a0, b0, acc[0][0], 0, 0, 0);
            acc[0][1] = __builtin_amdgcn_mfma_f32_16x16x32_bf16(a0, b1, acc[0][1], 0, 0, 0);
            acc[0][2] = __builtin_amdgcn_mfma_f32_16x16x32_bf16(a0, b2, acc[0][2], 0, 0, 0);
            acc[0][3] = __builtin_amdgcn_mfma_f32_16x16x32_bf16(a0, b3, acc[0][3], 0, 0, 0);
            acc[1][0] = __builtin_amdgcn_mfma_f32_16x16x32_bf16(a1, b0, acc[1][0], 0, 0, 0);
            acc[1][1] = __builtin_amdgcn_mfma_f32_16x16x32_bf16(a1, b1, acc[1][1], 0, 0, 0);
            acc[1][2] = __builtin_amdgcn_mfma_f32_16x16x32_bf16(a1, b2, acc[1][2], 0, 0, 0);
            acc[1][3] = __builtin_amdgcn_mfma_f32_16x16x32_bf16(a1, b3, acc[1][3], 0, 0, 0);
        }
        __builtin_amdgcn_s_setprio(0);
        __builtin_amdgcn_sched_barrier(0);   // pin: all MFMAs before cvt/write

        // write qt(t+1) into the buffer compute(t-1) freed (all waves passed
        // B1 after finishing iter t-1 -> safe). Compiler inserts the counted
        // vmcnt before the first cvt use of pf.
        if (t < NQT - 1) {
            #pragma unroll
            for (int s = 0; s < 4; ++s) {
                const int sid  = s * 256 + tid;
                const int crow = sid >> 3;
                const int sl   = sid & 7;
                *(bf16x8*)&sB[(t + 1) & 1][crow * 64 + sl * 8] =
                    cvt8(pf[2 * s], pf[2 * s + 1]);
            }
        }

        // epilogue once per position (ks==3): acc holds the full K dot now
        if (ks == 3) {
            const int pos = t >> 2;
            const int jb = pos * 128 + wn * 64 + l16;
            #pragma unroll
            for (int tm = 0; tm < 2; ++tm)
                #pragma unroll
                for (int r = 0; r < 4; ++r)
                    #pragma unroll
                    for (int tn = 0; tn < 4; ++tn) {
                        const u64 pk = ((u64)enc_f32(acc[tm][tn][r]) << 32)
                                     | (unsigned int)(~(unsigned int)(jb + tn * 16));
                        rowbest[tm][r] = pmax(rowbest[tm][r], pk);
                    }
            #pragma unroll
            for (int tn = 0; tn < 4; ++tn) {
                float cv = acc[0][tn][0];
                int   ca = a0q;
                #pragma unroll
                for (int tm = 0; tm < 2; ++tm)
                    #pragma unroll
                    for (int r = 0; r < 4; ++r) {
                        if (tm == 0 && r == 0) continue;
                        if (acc[tm][tn][r] > cv) { cv = acc[tm][tn][r]; ca = a0q + tm * 16 + r; }
                    }
                u64 pk = ((u64)enc_f32(cv) << 32) | (unsigned int)(~(unsigned int)ca);
                pk = pmax(pk, __shfl_xor(pk, 16));   // combine quads (rows)
                pk = pmax(pk, __shfl_xor(pk, 32));
                if (quad == 0)
                    colpart[colbase + pos * 128 + wn * 64 + tn * 16 + l16] = pk;
            }
        }
    }

    // ---- row argmax finish: reduce over l16 lanes, combine wn via LDS ----
    #pragma unroll
    for (int tm = 0; tm < 2; ++tm)
        #pragma unroll
        for (int r = 0; r < 4; ++r) {
            u64 pk = rowbest[tm][r];
            pk = pmax(pk, __shfl_xor(pk, 1));
            pk = pmax(pk, __shfl_xor(pk, 2));
            pk = pmax(pk, __shfl_xor(pk, 4));
            pk = pmax(pk, __shfl_xor(pk, 8));
            if (l16 == 0) sRow[wn][wm * 32 + tm * 16 + quad * 4 + r] = pk;
        }
    __syncthreads();
    if (tid < 64) {
        const u64 m = pmax(sRow[0][tid], sRow[1][tid]);
        max2[(size_t)b * L + rt * 64 + tid] = (int)(~(unsigned int)m) & (L - 1);
    }
}

// Kernel 2: reduce col partials (32-deep: rt x wm) + mutual-NN + mean.
__global__ __launch_bounds__(1024) void finalize_kernel(
    const u64* __restrict__ colpart,  // [B][32][L]
    const int* __restrict__ max2,     // [B][L]
    float* __restrict__ out)
{
    __shared__ int sMax2[L];
    __shared__ float sSum[16];
    __shared__ int sCnt[16];
    const int b = blockIdx.x;
    const int j = threadIdx.x;        // 0..1023

    sMax2[j] = max2[(size_t)b * L + j];

    u64 cb = 0ull;
    #pragma unroll
    for (int k = 0; k < 32; ++k)
        cb = pmax(cb, colpart[((size_t)b * 32 + k) * L + j]);
    __syncthreads();

    const int a = (int)(~(unsigned int)cb) & (L - 1);      // max1[j]
    const float val = dec_f32((unsigned int)(cb >> 32));   // sims[j]
    const bool mut = (sMax2[a] == j);                      // mutual NN
    float sum = mut ? val : 0.f;
    int   cnt = mut ? 1 : 0;

    #pragma unroll
    for (int o = 32; o >= 1; o >>= 1) {
        sum += __shfl_down(sum, o);
        cnt += __shfl_down(cnt, o);
    }
    if ((j & 63) == 0) { sSum[j >> 6] = sum; sCnt[j >> 6] = cnt; }
    __syncthreads();
    if (j == 0) {
        float S = 0.f;
        int   C = 0;
        #pragma unroll
        for (int i = 0; i < 16; ++i) { S += sSum[i]; C += sCnt[i]; }
        out[b] = S / fmaxf((float)C, 1.0f);
    }
}

extern "C" void kernel_launch(void* const* d_in, const int* in_sizes, int n_in,
                              void* d_out, int out_size, void* d_ws, size_t ws_size,
                              hipStream_t stream) {
    const float* q = (const float*)d_in[0];   // feats1 (queries)
    const float* p = (const float*)d_in[1];   // feats2 (preds)
    float* out = (float*)d_out;

    // ws layout: colpart [32][32][1024] u64 (8 MiB) | max2 [32][1024] int.
    // Every slot written before read -> no init needed. No convert buffers.
    u64* colpart = (u64*)d_ws;
    int* max2 = (int*)(colpart + (size_t)BATCH * 32 * L);

    mm_argmax_kernel<<<BATCH * NRT, 256, 0, stream>>>(q, p, colpart, max2);
    finalize_kernel<<<BATCH, 1024, 0, stream>>>(colpart, max2, out);
}